// Round 1
// baseline (125.806 us; speedup 1.0000x reference)
//
#include <hip/hip_runtime.h>

#define N_TOK   16384
#define DMODEL  2048
#define N_EXP   16
#define CAP     2048   // 2 * N_TOK / N_EXP

// ---------------------------------------------------------------------------
// Kernel 1: per-token argmax over 16 scores (first-max-index semantics, like
// jnp.argmax). Writes int expert index to ws and float expert index to d_out.
// ---------------------------------------------------------------------------
__global__ void k_argmax(const float* __restrict__ score,
                         int* __restrict__ eidx,
                         float* __restrict__ expert_f) {
    int t = blockIdx.x * blockDim.x + threadIdx.x;
    if (t >= N_TOK) return;
    const float4* s4 = (const float4*)(score + (size_t)t * N_EXP);
    float4 a = s4[0], b = s4[1], c = s4[2], d = s4[3];
    float v[16] = {a.x,a.y,a.z,a.w, b.x,b.y,b.z,b.w,
                   c.x,c.y,c.z,c.w, d.x,d.y,d.z,d.w};
    float best = v[0];
    int bi = 0;
#pragma unroll
    for (int j = 1; j < 16; ++j) {
        if (v[j] > best) { best = v[j]; bi = j; }   // strict > keeps first max
    }
    eidx[t] = bi;
    expert_f[t] = (float)bi;
}

// ---------------------------------------------------------------------------
// Kernel 2: order-preserving per-expert prefix count (pos), keep flag, and the
// inverse slot->token map. Single block of 1024 threads (16 waves), 16 chunks
// of 1024 tokens, sequential in token order so pos matches cumsum semantics.
// ---------------------------------------------------------------------------
__global__ void __launch_bounds__(1024)
k_scan(const int* __restrict__ eidx,
       int* __restrict__ slot_map,
       float* __restrict__ pos_f,
       float* __restrict__ keep_f) {
    __shared__ int wave_counts[16][N_EXP];  // [wave][expert]
    __shared__ int running[N_EXP];          // tokens of expert e in prior chunks

    const int tid  = threadIdx.x;
    const int lane = tid & 63;
    const int wave = tid >> 6;
    const unsigned long long below = (1ull << lane) - 1ull;  // lanes < me

    if (tid < N_EXP) running[tid] = 0;
    __syncthreads();

    for (int chunk = 0; chunk < N_TOK / 1024; ++chunk) {
        const int t = chunk * 1024 + tid;
        const int e = eidx[t];

        int rank = 0;
#pragma unroll
        for (int ex = 0; ex < N_EXP; ++ex) {
            unsigned long long m = __ballot(e == ex);
            if (e == ex) rank = __popcll(m & below);
            if (lane == 0) wave_counts[wave][ex] = __popcll(m);
        }
        __syncthreads();

        // base from prior chunks + prior waves in this chunk + rank in wave
        int wp = 0;
        for (int w = 0; w < wave; ++w) wp += wave_counts[w][e];
        const int pos = running[e] + wp + rank;

        pos_f[t]  = (float)pos;
        keep_f[t] = (pos < CAP) ? 1.0f : 0.0f;
        if (pos < CAP) slot_map[e * CAP + pos] = t;

        __syncthreads();  // all reads of running[] done before update
        if (tid < N_EXP) {
            int s = 0;
#pragma unroll
            for (int w = 0; w < 16; ++w) s += wave_counts[w][tid];
            running[tid] += s;
        }
        __syncthreads();  // update visible (and wave_counts free) for next chunk
    }
}

// ---------------------------------------------------------------------------
// Kernel 3: fill dispatched[E][C][D]. One block per slot row; every element of
// the 256 MiB output written exactly once (copy token row or zeros).
// ---------------------------------------------------------------------------
__global__ void __launch_bounds__(256)
k_fill(const float* __restrict__ inputs,
       const int* __restrict__ slot_map,
       float* __restrict__ dispatched) {
    const int slot = blockIdx.x;              // e*CAP + c
    const int tok  = slot_map[slot];          // -1 if empty
    float4* out4 = (float4*)(dispatched + (size_t)slot * DMODEL);
    const int tid = threadIdx.x;
    if (tok >= 0) {
        const float4* in4 = (const float4*)(inputs + (size_t)tok * DMODEL);
        float4 x0 = in4[tid];
        float4 x1 = in4[tid + 256];
        out4[tid]       = x0;
        out4[tid + 256] = x1;
    } else {
        float4 z = {0.f, 0.f, 0.f, 0.f};
        out4[tid]       = z;
        out4[tid + 256] = z;
    }
}

// ---------------------------------------------------------------------------
extern "C" void kernel_launch(void* const* d_in, const int* in_sizes, int n_in,
                              void* d_out, int out_size, void* d_ws, size_t ws_size,
                              hipStream_t stream) {
    const float* inputs = (const float*)d_in[0];
    const float* score  = (const float*)d_in[1];

    float* out        = (float*)d_out;
    float* dispatched = out;                                   // E*CAP*DMODEL
    float* expert_f   = out + (size_t)N_EXP * CAP * DMODEL;    // N_TOK
    float* pos_f      = expert_f + N_TOK;                      // N_TOK
    float* keep_f     = pos_f + N_TOK;                         // N_TOK

    int* slot_map = (int*)d_ws;              // E*CAP ints
    int* eidx     = slot_map + N_EXP * CAP;  // N_TOK ints

    // slot_map := -1 (0xFFFFFFFF) every call (ws is not re-poisoned between
    // replays; must be deterministic)
    hipMemsetAsync(slot_map, 0xFF, (size_t)N_EXP * CAP * sizeof(int), stream);

    k_argmax<<<N_TOK / 256, 256, 0, stream>>>(score, eidx, expert_f);
    k_scan<<<1, 1024, 0, stream>>>(eidx, slot_map, pos_f, keep_f);
    k_fill<<<N_EXP * CAP, 256, 0, stream>>>(inputs, slot_map, dispatched);
}

// Round 2
// 92.222 us; speedup vs baseline: 1.3642x; 1.3642x over previous
//
#include <hip/hip_runtime.h>

#define N_TOK   16384
#define DMODEL  2048
#define N_EXP   16
#define CAP     2048           // 2 * N_TOK / N_EXP
#define CHUNK   256
#define N_CHUNK (N_TOK / CHUNK)  // 64

// ---------------------------------------------------------------------------
// K1: per-token argmax (first-max semantics) + per-chunk expert histogram.
// 64 blocks x 256 threads; each block owns one 256-token chunk.
// ---------------------------------------------------------------------------
__global__ void __launch_bounds__(256)
k_hist(const float* __restrict__ score,
       int* __restrict__ eidx,
       float* __restrict__ expert_f,
       int* __restrict__ hist) {
    const int tid = threadIdx.x;
    const int bid = blockIdx.x;
    const int t = bid * CHUNK + tid;

    const float4* s4 = (const float4*)(score + (size_t)t * N_EXP);
    float4 a = s4[0], b = s4[1], c = s4[2], d = s4[3];
    float v[16] = {a.x,a.y,a.z,a.w, b.x,b.y,b.z,b.w,
                   c.x,c.y,c.z,c.w, d.x,d.y,d.z,d.w};
    float best = v[0];
    int bi = 0;
#pragma unroll
    for (int j = 1; j < 16; ++j) {
        if (v[j] > best) { best = v[j]; bi = j; }  // strict > keeps first max
    }
    eidx[t] = bi;
    expert_f[t] = (float)bi;

    __shared__ int wh[4][N_EXP];
    const int wave = tid >> 6;
    const int lane = tid & 63;
#pragma unroll
    for (int ex = 0; ex < N_EXP; ++ex) {
        unsigned long long m = __ballot(bi == ex);
        if (lane == 0) wh[wave][ex] = __popcll(m);
    }
    __syncthreads();
    if (tid < N_EXP)
        hist[bid * N_EXP + tid] = wh[0][tid] + wh[1][tid] + wh[2][tid] + wh[3][tid];
}

// ---------------------------------------------------------------------------
// K2: exclusive prefix of hist over chunks, per expert. Tiny: all in LDS.
// base[c][e] = tokens of expert e in chunks < c; count[e] = total.
// ---------------------------------------------------------------------------
__global__ void __launch_bounds__(1024)
k_scan(const int* __restrict__ hist,
       int* __restrict__ base,
       int* __restrict__ count) {
    __shared__ int h[N_CHUNK * N_EXP];
    __shared__ int bl[N_CHUNK * N_EXP];
    const int tid = threadIdx.x;   // 1024 == N_CHUNK * N_EXP
    h[tid] = hist[tid];
    __syncthreads();
    if (tid < N_EXP) {
        int run = 0;
        for (int c = 0; c < N_CHUNK; ++c) {
            bl[c * N_EXP + tid] = run;
            run += h[c * N_EXP + tid];
        }
        count[tid] = run;
    }
    __syncthreads();
    base[tid] = bl[tid];
}

// ---------------------------------------------------------------------------
// K3: one dispatch, two roles.
//  blocks [0, N_TOK): token t — recompute rank-in-chunk via one ballot round,
//    pos = base[chunk][e] + rank; write pos/keep; copy row if kept.
//  blocks [N_TOK, N_TOK + E*CAP): slot s — zero iff slot is beyond count[e]
//    (filled slots are exactly [0, count[e]) since routing is order-dense).
// Every element of dispatched is written exactly once per call.
// ---------------------------------------------------------------------------
__global__ void __launch_bounds__(256)
k_fill(const float* __restrict__ inputs,
       const int* __restrict__ eidx,
       const int* __restrict__ base,
       const int* __restrict__ count,
       float* __restrict__ dispatched,
       float* __restrict__ pos_f,
       float* __restrict__ keep_f) {
    const int bid = blockIdx.x;
    const int tid = threadIdx.x;

    if (bid < N_TOK) {
        const int t = bid;
        const int chunk = t >> 8;
        const int tloc = t & (CHUNK - 1);
        const int e_t = eidx[t];                       // broadcast load
        const int ee = eidx[(chunk << 8) + tid];       // my chunk's experts
        const bool match = (ee == e_t) && (tid < tloc);
        unsigned long long m = __ballot(match);
        __shared__ int wcnt[4];
        if ((tid & 63) == 0) wcnt[tid >> 6] = __popcll(m);
        __syncthreads();
        const int rank = wcnt[0] + wcnt[1] + wcnt[2] + wcnt[3];
        const int pos = base[chunk * N_EXP + e_t] + rank;
        if (tid == 0) {
            pos_f[t]  = (float)pos;
            keep_f[t] = (pos < CAP) ? 1.0f : 0.0f;
        }
        if (pos < CAP) {
            const float4* in4 = (const float4*)(inputs + (size_t)t * DMODEL);
            float4* out4 = (float4*)(dispatched + ((size_t)e_t * CAP + pos) * DMODEL);
            out4[tid]         = in4[tid];
            out4[tid + CHUNK] = in4[tid + CHUNK];
        }
    } else {
        const int s = bid - N_TOK;                     // e*CAP + c
        const int e = s >> 11;
        const int c = s & (CAP - 1);
        if (c < count[e]) return;                      // occupied slot
        float4* out4 = (float4*)(dispatched + (size_t)s * DMODEL);
        const float4 z = {0.f, 0.f, 0.f, 0.f};
        out4[tid]         = z;
        out4[tid + CHUNK] = z;
    }
}

// ---------------------------------------------------------------------------
extern "C" void kernel_launch(void* const* d_in, const int* in_sizes, int n_in,
                              void* d_out, int out_size, void* d_ws, size_t ws_size,
                              hipStream_t stream) {
    const float* inputs = (const float*)d_in[0];
    const float* score  = (const float*)d_in[1];

    float* out        = (float*)d_out;
    float* dispatched = out;                                   // E*CAP*DMODEL
    float* expert_f   = out + (size_t)N_EXP * CAP * DMODEL;    // N_TOK
    float* pos_f      = expert_f + N_TOK;                      // N_TOK
    float* keep_f     = pos_f + N_TOK;                         // N_TOK

    int* eidx  = (int*)d_ws;                 // N_TOK
    int* hist  = eidx + N_TOK;               // N_CHUNK * N_EXP
    int* base  = hist + N_CHUNK * N_EXP;     // N_CHUNK * N_EXP
    int* count = base + N_CHUNK * N_EXP;     // N_EXP

    k_hist<<<N_CHUNK, CHUNK, 0, stream>>>(score, eidx, expert_f, hist);
    k_scan<<<1, 1024, 0, stream>>>(hist, base, count);
    k_fill<<<N_TOK + N_EXP * CAP, CHUNK, 0, stream>>>(
        inputs, eidx, base, count, dispatched, pos_f, keep_f);
}